// Round 3
// baseline (59.403 us; speedup 1.0000x reference)
//
#include <hip/hip_runtime.h>
#include <math.h>

#define T_TOTAL   131072
#define POSE_FLTS (131072 * 216)      // 28311552
#define BT        64                  // timesteps per scan unit / fused block
#define NBLK      (T_TOTAL / BT)      // 2048
#define F4_PER_BLK (BT * 54)          // 3456 float4 per fused block
#define FLOOR_YC  (-0.93f)
#define GRAV_Y    (-0.0018f)
#define NEG_INF   (-INFINITY)

// ---------------- small math helpers (constant-indexed after inlining) ------

__device__ __forceinline__ void mat3mul(const float* A, const float* B, float* C) {
#pragma unroll
    for (int r = 0; r < 3; ++r) {
#pragma unroll
        for (int c = 0; c < 3; ++c) {
            C[r * 3 + c] = fmaf(A[r * 3 + 2], B[6 + c],
                           fmaf(A[r * 3 + 1], B[3 + c],
                                A[r * 3 + 0] * B[c]));
        }
    }
}

__device__ __forceinline__ void mva(const float* R, const float* b,
                                    const float* pin, float* pout) {
#pragma unroll
    for (int r = 0; r < 3; ++r) {
        pout[r] = pin[r] + fmaf(R[r * 3 + 2], b[2],
                            fmaf(R[r * 3 + 1], b[1], R[r * 3 + 0] * b[0]));
    }
}

// select foot component via cndmask chain (no scratch from runtime indexing)
__device__ __forceinline__ float sel_foot(const float f[12], int idx, int c) {
    float r = f[0 + c];
    r = (idx == 1) ? f[3 + c] : r;
    r = (idx == 2) ? f[6 + c] : r;
    r = (idx == 3) ? f[9 + c] : r;
    return r;
}

// FK for one timestep. Needs joints (lower idx) 0,1,2,4,5,7,8 at float
// offsets 0,9,18,36,45,63,72. Load via aligned float4: [0,28),[36,56),[60,84).
__device__ __forceinline__ void fk_feet(const float* __restrict__ P,
                                        const float* __restrict__ bone,
                                        float feet[12], float* fmin) {
    float Pl[84];
    const float4* p4 = (const float4*)P;   // 864 B per timestep -> 16B aligned
#pragma unroll
    for (int i = 0; i < 7; ++i) {
        float4 q = p4[i];
        Pl[4*i] = q.x; Pl[4*i+1] = q.y; Pl[4*i+2] = q.z; Pl[4*i+3] = q.w;
    }
#pragma unroll
    for (int i = 9; i < 14; ++i) {
        float4 q = p4[i];
        Pl[4*i] = q.x; Pl[4*i+1] = q.y; Pl[4*i+2] = q.z; Pl[4*i+3] = q.w;
    }
#pragma unroll
    for (int i = 15; i < 21; ++i) {
        float4 q = p4[i];
        Pl[4*i] = q.x; Pl[4*i+1] = q.y; Pl[4*i+2] = q.z; Pl[4*i+3] = q.w;
    }

    const float* M0 = Pl + 0;
    const float* M1 = Pl + 9;
    const float* M2 = Pl + 18;
    const float* M3 = Pl + 36;
    const float* M4 = Pl + 45;
    const float* M5 = Pl + 63;
    const float* M6 = Pl + 72;

    float R1[9], R2[9], R3[9], R4[9], R5[9], R6[9];
    mat3mul(M0, M1, R1);
    mat3mul(M0, M2, R2);
    mat3mul(R1, M3, R3);
    mat3mul(R2, M4, R4);
    mat3mul(R3, M5, R5);
    mat3mul(R4, M6, R6);

    float p0[3] = {bone[0], bone[1], bone[2]};
    float p1[3], p2[3], p3[3], p4a[3], p5[3], p6[3], p7[3], p8[3];
    mva(M0, bone + 3,  p0, p1);
    mva(M0, bone + 6,  p0, p2);
    mva(R1, bone + 9,  p1, p3);
    mva(R2, bone + 12, p2, p4a);
    mva(R3, bone + 15, p3, p5);
    mva(R4, bone + 18, p4a, p6);
    mva(R5, bone + 21, p5, p7);
    mva(R6, bone + 24, p6, p8);

    // FEET = [7,5,8,6]
    feet[0] = p7[0]; feet[1]  = p7[1]; feet[2]  = p7[2];
    feet[3] = p5[0]; feet[4]  = p5[1]; feet[5]  = p5[2];
    feet[6] = p8[0]; feet[7]  = p8[1]; feet[8]  = p8[2];
    feet[9] = p6[0]; feet[10] = p6[1]; feet[11] = p6[2];
    *fmin = fminf(fminf(p5[1], p6[1]), fminf(p7[1], p8[1]));
}

// inclusive wave scan (non-commutative compose, earlier = lower lane)
__device__ __forceinline__ void wave_incl_scan(float& Sx, float& Sz,
                                               float& A, float& B, int lane) {
#pragma unroll
    for (int off = 1; off < 64; off <<= 1) {
        float ox = __shfl_up(Sx, off, 64);
        float oz = __shfl_up(Sz, off, 64);
        float oA = __shfl_up(A, off, 64);
        float oB = __shfl_up(B, off, 64);
        if (lane >= off) {
            Sx += ox;
            Sz += oz;
            B = fmaxf(oB + A, B);  // B uses pre-update A
            A = oA + A;
        }
    }
}

// ---------------- kernels ---------------------------------------------------

// Fused: copy block's 64-timestep pose slice (all 256 threads) +
// FK once per timestep (wave 0, neighbor feet via shfl) + per-element scan
// operand to ws + unit aggregate. No LDS, no __syncthreads.
__global__ __launch_bounds__(256) void k_fused(const float* __restrict__ pose,
                                               const float* __restrict__ bone,
                                               const int* __restrict__ index,
                                               float4* __restrict__ outPose4,
                                               float4* __restrict__ vws,
                                               float4* __restrict__ wsAgg) {
    int b = blockIdx.x, tid = threadIdx.x;

    // ---- copy this block's 64x216 floats = 3456 float4 over 256 threads ----
    const float4* src = (const float4*)pose + (size_t)b * F4_PER_BLK;
    float4*       dst = outPose4            + (size_t)b * F4_PER_BLK;
#pragma unroll
    for (int k = 0; k < 13; ++k) dst[k * 256 + tid] = src[k * 256 + tid];
    if (tid < 128) dst[13 * 256 + tid] = src[13 * 256 + tid];

    // ---- wave 0: FK + scan operand + unit aggregate ------------------------
    if (tid < 64) {
        int lane = tid;
        int t = b * BT + lane;

        float feet[12], fmin;
        fk_feet(pose + (size_t)t * 216, bone, feet, &fmin);

        float fp[12];
#pragma unroll
        for (int k = 0; k < 12; ++k) fp[k] = __shfl_up(feet[k], 1, 64);
        if (lane == 0 && b > 0) {
            float f2[12], m2;
            fk_feet(pose + (size_t)(t - 1) * 216, bone, f2, &m2);
#pragma unroll
            for (int k = 0; k < 12; ++k) fp[k] = f2[k];
        }

        float vx, vy, vz;
        if (t == 0) {
            vx = 0.f; vy = GRAV_Y; vz = 0.f;
        } else {
            int idx = index[t];
            vx = sel_foot(fp, idx, 0) - sel_foot(feet, idx, 0);
            vy = GRAV_Y + sel_foot(fp, idx, 1) - sel_foot(feet, idx, 1);
            vz = sel_foot(fp, idx, 2) - sel_foot(feet, idx, 2);
        }
        float A = vy;
        float B = FLOOR_YC - fmin;
        vws[t] = make_float4(vx, vz, A, B);

        float Sx = vx, Sz = vz;
        wave_incl_scan(Sx, Sz, A, B, lane);
        if (lane == 63) wsAgg[b] = make_float4(Sx, Sz, A, B);
    }
}

// Scan of 2048 unit aggregates -> per-unit entering state (x, z, root_y).
// One block of 1024 threads; each thread pre-composes a pair.
__global__ __launch_bounds__(1024) void k_phase2(const float4* __restrict__ wsAgg,
                                                 float4* __restrict__ wsIn) {
    __shared__ float sx[1024], sz[1024], sa[1024], sb[1024];
    int tid = threadIdx.x;

    float4 a0 = wsAgg[2 * tid];
    float4 a1 = wsAgg[2 * tid + 1];
    // compose: a0 then a1
    float cx = a0.x + a1.x;
    float cz = a0.y + a1.y;
    float cb = fmaxf(a0.w + a1.z, a1.w);
    float ca = a0.z + a1.z;
    sx[tid] = cx; sz[tid] = cz; sa[tid] = ca; sb[tid] = cb;
    __syncthreads();

    for (int off = 1; off < 1024; off <<= 1) {
        float px = 0.f, pz = 0.f, pa = 0.f, pb = NEG_INF;
        bool h = (tid >= off);
        if (h) { px = sx[tid - off]; pz = sz[tid - off]; pa = sa[tid - off]; pb = sb[tid - off]; }
        __syncthreads();
        if (h) {
            float qa = sa[tid], qb = sb[tid];
            sx[tid] = px + sx[tid];
            sz[tid] = pz + sz[tid];
            sb[tid] = fmaxf(pb + qa, qb);
            sa[tid] = pa + qa;
        }
        __syncthreads();
    }

    // exclusive prefix for pair tid
    float ex = 0.f, ez = 0.f, ea = 0.f, eb = NEG_INF;
    if (tid > 0) { ex = sx[tid - 1]; ez = sz[tid - 1]; ea = sa[tid - 1]; eb = sb[tid - 1]; }

    // unit 2*tid entering state (apply prefix to r0 = 0)
    wsIn[2 * tid] = make_float4(ex, ez, fmaxf(ea, eb), 0.f);

    // unit 2*tid+1 entering state = prefix ∘ a0
    float fx = ex + a0.x;
    float fz = ez + a0.y;
    float fb = fmaxf(eb + a0.z, a0.w);
    float fa = ea + a0.z;
    wsIn[2 * tid + 1] = make_float4(fx, fz, fmaxf(fa, fb), 0.f);
}

// Final: each wave handles one 64-step unit; no cross-wave composition needed.
__global__ __launch_bounds__(256) void k_phase3(const float4* __restrict__ vws,
                                                const float4* __restrict__ wsIn,
                                                float* __restrict__ trans) {
    int tid = threadIdx.x, b = blockIdx.x;
    int lane = tid & 63, wv = tid >> 6;
    int u = b * 4 + wv;
    int t = u * BT + lane;

    float4 v = vws[t];
    float ix = v.x, iz = v.y, iA = v.z, iB = v.w;
    wave_incl_scan(ix, iz, iA, iB, lane);

    float4 bin = wsIn[u];
    trans[(size_t)t * 3 + 0] = bin.x + ix;
    trans[(size_t)t * 3 + 1] = fmaxf(bin.z + iA, iB);
    trans[(size_t)t * 3 + 2] = bin.y + iz;
}

// ---------------- launch -----------------------------------------------------

extern "C" void kernel_launch(void* const* d_in, const int* in_sizes, int n_in,
                              void* d_out, int out_size, void* d_ws, size_t ws_size,
                              hipStream_t stream) {
    const float* pose  = (const float*)d_in[0];
    const float* bone  = (const float*)d_in[1];
    const int*   index = (const int*)d_in[2];
    float* out   = (float*)d_out;
    float* trans = out + POSE_FLTS;

    float4* vws   = (float4*)d_ws;         // T entries (2 MB)
    float4* wsAgg = vws + T_TOTAL;         // NBLK entries
    float4* wsIn  = wsAgg + NBLK;          // NBLK entries

    k_fused <<<NBLK, 256, 0, stream>>>(pose, bone, index, (float4*)out, vws, wsAgg);
    k_phase2<<<1,    1024, 0, stream>>>(wsAgg, wsIn);
    k_phase3<<<T_TOTAL / 256, 256, 0, stream>>>(vws, wsIn, trans);
}

// Round 5
// 57.285 us; speedup vs baseline: 1.0370x; 1.0370x over previous
//
#include <hip/hip_runtime.h>
#include <math.h>

#define T_TOTAL   131072
#define POSE_FLTS (131072 * 216)       // 28311552
#define POSE_F4   (POSE_FLTS / 4)      // 7077888
#define NF        512                  // FK blocks, 256 timesteps each
#define NC        1536                 // copy blocks
#define CPY_S     (NC * 256)           // 393216 threads in copy role
#define NU        2048                 // scan units of 64 timesteps
#define FLOOR_YC  (-0.93f)
#define GRAV_Y    (-0.0018f)
#define NEG_INF   (-INFINITY)

typedef float floatx4 __attribute__((ext_vector_type(4)));

// ---------------- small math helpers (constant-indexed after inlining) ------

__device__ __forceinline__ void mat3mul(const float* A, const float* B, float* C) {
#pragma unroll
    for (int r = 0; r < 3; ++r) {
#pragma unroll
        for (int c = 0; c < 3; ++c) {
            C[r * 3 + c] = fmaf(A[r * 3 + 2], B[6 + c],
                           fmaf(A[r * 3 + 1], B[3 + c],
                                A[r * 3 + 0] * B[c]));
        }
    }
}

__device__ __forceinline__ void mva(const float* R, const float* b,
                                    const float* pin, float* pout) {
#pragma unroll
    for (int r = 0; r < 3; ++r) {
        pout[r] = pin[r] + fmaf(R[r * 3 + 2], b[2],
                            fmaf(R[r * 3 + 1], b[1], R[r * 3 + 0] * b[0]));
    }
}

__device__ __forceinline__ float sel_foot(const float f[12], int idx, int c) {
    float r = f[0 + c];
    r = (idx == 1) ? f[3 + c] : r;
    r = (idx == 2) ? f[6 + c] : r;
    r = (idx == 3) ? f[9 + c] : r;
    return r;
}

// FK for one timestep. Needs joints (lower idx) 0,1,2,4,5,7,8 at float
// offsets 0,9,18,36,45,63,72. Load via aligned float4: [0,28),[36,56),[60,84).
__device__ __forceinline__ void fk_feet(const float* __restrict__ P,
                                        const float* __restrict__ bone,
                                        float feet[12], float* fmin) {
    float Pl[84];
    const floatx4* p4 = (const floatx4*)P;   // 864 B per timestep -> 16B aligned
#pragma unroll
    for (int i = 0; i < 7; ++i) {
        floatx4 q = p4[i];
        Pl[4*i] = q.x; Pl[4*i+1] = q.y; Pl[4*i+2] = q.z; Pl[4*i+3] = q.w;
    }
#pragma unroll
    for (int i = 9; i < 14; ++i) {
        floatx4 q = p4[i];
        Pl[4*i] = q.x; Pl[4*i+1] = q.y; Pl[4*i+2] = q.z; Pl[4*i+3] = q.w;
    }
#pragma unroll
    for (int i = 15; i < 21; ++i) {
        floatx4 q = p4[i];
        Pl[4*i] = q.x; Pl[4*i+1] = q.y; Pl[4*i+2] = q.z; Pl[4*i+3] = q.w;
    }

    const float* M0 = Pl + 0;
    const float* M1 = Pl + 9;
    const float* M2 = Pl + 18;
    const float* M3 = Pl + 36;
    const float* M4 = Pl + 45;
    const float* M5 = Pl + 63;
    const float* M6 = Pl + 72;

    float R1[9], R2[9], R3[9], R4[9], R5[9], R6[9];
    mat3mul(M0, M1, R1);
    mat3mul(M0, M2, R2);
    mat3mul(R1, M3, R3);
    mat3mul(R2, M4, R4);
    mat3mul(R3, M5, R5);
    mat3mul(R4, M6, R6);

    float p0[3] = {bone[0], bone[1], bone[2]};
    float p1[3], p2[3], p3[3], p4a[3], p5[3], p6[3], p7[3], p8[3];
    mva(M0, bone + 3,  p0, p1);
    mva(M0, bone + 6,  p0, p2);
    mva(R1, bone + 9,  p1, p3);
    mva(R2, bone + 12, p2, p4a);
    mva(R3, bone + 15, p3, p5);
    mva(R4, bone + 18, p4a, p6);
    mva(R5, bone + 21, p5, p7);
    mva(R6, bone + 24, p6, p8);

    // FEET = [7,5,8,6]
    feet[0] = p7[0]; feet[1]  = p7[1]; feet[2]  = p7[2];
    feet[3] = p5[0]; feet[4]  = p5[1]; feet[5]  = p5[2];
    feet[6] = p8[0]; feet[7]  = p8[1]; feet[8]  = p8[2];
    feet[9] = p6[0]; feet[10] = p6[1]; feet[11] = p6[2];
    *fmin = fminf(fminf(p5[1], p6[1]), fminf(p7[1], p8[1]));
}

// inclusive wave scan (non-commutative compose, earlier = lower lane)
__device__ __forceinline__ void wave_incl_scan(float& Sx, float& Sz,
                                               float& A, float& B, int lane) {
#pragma unroll
    for (int off = 1; off < 64; off <<= 1) {
        float ox = __shfl_up(Sx, off, 64);
        float oz = __shfl_up(Sz, off, 64);
        float oA = __shfl_up(A, off, 64);
        float oB = __shfl_up(B, off, 64);
        if (lane >= off) {
            Sx += ox;
            Sz += oz;
            B = fmaxf(oB + A, B);  // B uses pre-update A
            A = oA + A;
        }
    }
}

// ---------------- kernels ---------------------------------------------------

// Heterogeneous grid: blocks [0,NF) do FK+scan-operand; blocks [NF,NF+NC)
// do the pure streaming copy. FK latency hides under copy bandwidth.
__global__ __launch_bounds__(256) void k_fused(const float* __restrict__ pose,
                                               const float* __restrict__ bone,
                                               const int* __restrict__ index,
                                               floatx4* __restrict__ outPose4,
                                               float4* __restrict__ vws,
                                               float4* __restrict__ wsAgg) {
    int tid = threadIdx.x;

    if (blockIdx.x >= NF) {
        // ---- copy role: 18 float4 per thread, 2 batches of 9 in flight ----
        int cb = blockIdx.x - NF;
        size_t g = (size_t)cb * 256 + tid;
        const floatx4* __restrict__ src = (const floatx4*)pose;
        floatx4 r[9];
#pragma unroll
        for (int bat = 0; bat < 2; ++bat) {
#pragma unroll
            for (int j = 0; j < 9; ++j)
                r[j] = src[g + (size_t)(bat * 9 + j) * CPY_S];
#pragma unroll
            for (int j = 0; j < 9; ++j)
                __builtin_nontemporal_store(r[j], &outPose4[g + (size_t)(bat * 9 + j) * CPY_S]);
        }
        return;
    }

    // ---- FK role: one timestep per thread --------------------------------
    int b = blockIdx.x;
    int t = b * 256 + tid;
    int lane = tid & 63, wv = tid >> 6;

    float feet[12], fmin;
    fk_feet(pose + (size_t)t * 216, bone, feet, &fmin);

    __shared__ float edge[4][12];       // lane-63 feet of each wave
    if (lane == 63) {
#pragma unroll
        for (int k = 0; k < 12; ++k) edge[wv][k] = feet[k];
    }
    __syncthreads();

    float fp[12];
#pragma unroll
    for (int k = 0; k < 12; ++k) fp[k] = __shfl_up(feet[k], 1, 64);
    if (lane == 0) {
        if (wv > 0) {
#pragma unroll
            for (int k = 0; k < 12; ++k) fp[k] = edge[wv - 1][k];
        } else if (b > 0) {
            float f2[12], m2;
            fk_feet(pose + (size_t)(t - 1) * 216, bone, f2, &m2);
#pragma unroll
            for (int k = 0; k < 12; ++k) fp[k] = f2[k];
        }
    }

    float vx, vy, vz;
    if (t == 0) {
        vx = 0.f; vy = GRAV_Y; vz = 0.f;
    } else {
        int idx = index[t];
        vx = sel_foot(fp, idx, 0) - sel_foot(feet, idx, 0);
        vy = GRAV_Y + sel_foot(fp, idx, 1) - sel_foot(feet, idx, 1);
        vz = sel_foot(fp, idx, 2) - sel_foot(feet, idx, 2);
    }
    float A = vy;
    float B = FLOOR_YC - fmin;
    vws[t] = make_float4(vx, vz, A, B);

    // wave == one 64-step unit; publish unit aggregate directly
    float Sx = vx, Sz = vz;
    wave_incl_scan(Sx, Sz, A, B, lane);
    if (lane == 63) wsAgg[b * 4 + wv] = make_float4(Sx, Sz, A, B);
}

// Scan of 2048 unit aggregates -> per-unit entering state (x, z, root_y).
// One block of 1024 threads; each thread pre-composes a pair.
__global__ __launch_bounds__(1024) void k_phase2(const float4* __restrict__ wsAgg,
                                                 float4* __restrict__ wsIn) {
    __shared__ float sx[1024], sz[1024], sa[1024], sb[1024];
    int tid = threadIdx.x;

    float4 a0 = wsAgg[2 * tid];
    float4 a1 = wsAgg[2 * tid + 1];
    float cx = a0.x + a1.x;
    float cz = a0.y + a1.y;
    float cb = fmaxf(a0.w + a1.z, a1.w);
    float ca = a0.z + a1.z;
    sx[tid] = cx; sz[tid] = cz; sa[tid] = ca; sb[tid] = cb;
    __syncthreads();

    for (int off = 1; off < 1024; off <<= 1) {
        float px = 0.f, pz = 0.f, pa = 0.f, pb = NEG_INF;
        bool h = (tid >= off);
        if (h) { px = sx[tid - off]; pz = sz[tid - off]; pa = sa[tid - off]; pb = sb[tid - off]; }
        __syncthreads();
        if (h) {
            float qa = sa[tid], qb = sb[tid];
            sx[tid] = px + sx[tid];
            sz[tid] = pz + sz[tid];
            sb[tid] = fmaxf(pb + qa, qb);
            sa[tid] = pa + qa;
        }
        __syncthreads();
    }

    float ex = 0.f, ez = 0.f, ea = 0.f, eb = NEG_INF;
    if (tid > 0) { ex = sx[tid - 1]; ez = sz[tid - 1]; ea = sa[tid - 1]; eb = sb[tid - 1]; }

    wsIn[2 * tid] = make_float4(ex, ez, fmaxf(ea, eb), 0.f);

    float fx = ex + a0.x;
    float fz = ez + a0.y;
    float fb = fmaxf(eb + a0.z, a0.w);
    float fa = ea + a0.z;
    wsIn[2 * tid + 1] = make_float4(fx, fz, fmaxf(fa, fb), 0.f);
}

// Final: each wave handles one 64-step unit; no cross-wave composition needed.
__global__ __launch_bounds__(256) void k_phase3(const float4* __restrict__ vws,
                                                const float4* __restrict__ wsIn,
                                                float* __restrict__ trans) {
    int tid = threadIdx.x, b = blockIdx.x;
    int lane = tid & 63, wv = tid >> 6;
    int u = b * 4 + wv;
    int t = u * 64 + lane;

    float4 v = vws[t];
    float ix = v.x, iz = v.y, iA = v.z, iB = v.w;
    wave_incl_scan(ix, iz, iA, iB, lane);

    float4 bin = wsIn[u];
    trans[(size_t)t * 3 + 0] = bin.x + ix;
    trans[(size_t)t * 3 + 1] = fmaxf(bin.z + iA, iB);
    trans[(size_t)t * 3 + 2] = bin.y + iz;
}

// ---------------- launch -----------------------------------------------------

extern "C" void kernel_launch(void* const* d_in, const int* in_sizes, int n_in,
                              void* d_out, int out_size, void* d_ws, size_t ws_size,
                              hipStream_t stream) {
    const float* pose  = (const float*)d_in[0];
    const float* bone  = (const float*)d_in[1];
    const int*   index = (const int*)d_in[2];
    float* out   = (float*)d_out;
    float* trans = out + POSE_FLTS;

    float4* vws   = (float4*)d_ws;         // T entries (2 MB)
    float4* wsAgg = vws + T_TOTAL;         // NU entries
    float4* wsIn  = wsAgg + NU;            // NU entries

    k_fused <<<NF + NC, 256, 0, stream>>>(pose, bone, index, (floatx4*)out, vws, wsAgg);
    k_phase2<<<1, 1024, 0, stream>>>(wsAgg, wsIn);
    k_phase3<<<T_TOTAL / 256, 256, 0, stream>>>(vws, wsIn, trans);
}

// Round 6
// 52.749 us; speedup vs baseline: 1.1261x; 1.0860x over previous
//
#include <hip/hip_runtime.h>
#include <math.h>

#define T_TOTAL   131072
#define POSE_FLTS (131072 * 216)       // 28311552
#define BT        64                   // timesteps per block = one scan unit
#define NB        (T_TOTAL / BT)       // 2048 blocks / units
#define F4PB      (BT * 54)            // 3456 float4 per block slice
#define TS_LDS    84                   // floats kept per timestep in LDS
#define FLOOR_YC  (-0.93f)
#define GRAV_Y    (-0.0018f)
#define NEG_INF   (-INFINITY)

typedef float floatx4 __attribute__((ext_vector_type(4)));

// ---------------- small math helpers (constant-indexed after inlining) ------

__device__ __forceinline__ void mat3mul(const float* A, const float* B, float* C) {
#pragma unroll
    for (int r = 0; r < 3; ++r) {
#pragma unroll
        for (int c = 0; c < 3; ++c) {
            C[r * 3 + c] = fmaf(A[r * 3 + 2], B[6 + c],
                           fmaf(A[r * 3 + 1], B[3 + c],
                                A[r * 3 + 0] * B[c]));
        }
    }
}

__device__ __forceinline__ void mva(const float* R, const float* b,
                                    const float* pin, float* pout) {
#pragma unroll
    for (int r = 0; r < 3; ++r) {
        pout[r] = pin[r] + fmaf(R[r * 3 + 2], b[2],
                            fmaf(R[r * 3 + 1], b[1], R[r * 3 + 0] * b[0]));
    }
}

__device__ __forceinline__ float sel_foot(const float f[12], int idx, int c) {
    float r = f[0 + c];
    r = (idx == 1) ? f[3 + c] : r;
    r = (idx == 2) ? f[6 + c] : r;
    r = (idx == 3) ? f[9 + c] : r;
    return r;
}

// FK for one timestep. P points at either global pose+t*216 or an LDS tile of
// floats [0,84) of the timestep (same indices: float4 i covers floats 4i..4i+3
// for i in {0..6, 9..13, 15..20}; joints at float offsets 0,9,18,36,45,63,72).
__device__ __forceinline__ void fk_feet(const float* __restrict__ P,
                                        const float* __restrict__ bone,
                                        float feet[12], float* fmin) {
    float Pl[84];
    const floatx4* p4 = (const floatx4*)P;   // 16B-aligned in both cases
#pragma unroll
    for (int i = 0; i < 7; ++i) {
        floatx4 q = p4[i];
        Pl[4*i] = q.x; Pl[4*i+1] = q.y; Pl[4*i+2] = q.z; Pl[4*i+3] = q.w;
    }
#pragma unroll
    for (int i = 9; i < 14; ++i) {
        floatx4 q = p4[i];
        Pl[4*i] = q.x; Pl[4*i+1] = q.y; Pl[4*i+2] = q.z; Pl[4*i+3] = q.w;
    }
#pragma unroll
    for (int i = 15; i < 21; ++i) {
        floatx4 q = p4[i];
        Pl[4*i] = q.x; Pl[4*i+1] = q.y; Pl[4*i+2] = q.z; Pl[4*i+3] = q.w;
    }

    const float* M0 = Pl + 0;
    const float* M1 = Pl + 9;
    const float* M2 = Pl + 18;
    const float* M3 = Pl + 36;
    const float* M4 = Pl + 45;
    const float* M5 = Pl + 63;
    const float* M6 = Pl + 72;

    float R1[9], R2[9], R3[9], R4[9], R5[9], R6[9];
    mat3mul(M0, M1, R1);
    mat3mul(M0, M2, R2);
    mat3mul(R1, M3, R3);
    mat3mul(R2, M4, R4);
    mat3mul(R3, M5, R5);
    mat3mul(R4, M6, R6);

    float p0[3] = {bone[0], bone[1], bone[2]};
    float p1[3], p2[3], p3[3], p4a[3], p5[3], p6[3], p7[3], p8[3];
    mva(M0, bone + 3,  p0, p1);
    mva(M0, bone + 6,  p0, p2);
    mva(R1, bone + 9,  p1, p3);
    mva(R2, bone + 12, p2, p4a);
    mva(R3, bone + 15, p3, p5);
    mva(R4, bone + 18, p4a, p6);
    mva(R5, bone + 21, p5, p7);
    mva(R6, bone + 24, p6, p8);

    // FEET = [7,5,8,6]
    feet[0] = p7[0]; feet[1]  = p7[1]; feet[2]  = p7[2];
    feet[3] = p5[0]; feet[4]  = p5[1]; feet[5]  = p5[2];
    feet[6] = p8[0]; feet[7]  = p8[1]; feet[8]  = p8[2];
    feet[9] = p6[0]; feet[10] = p6[1]; feet[11] = p6[2];
    *fmin = fminf(fminf(p5[1], p6[1]), fminf(p7[1], p8[1]));
}

// inclusive wave scan (non-commutative compose, earlier = lower lane)
__device__ __forceinline__ void wave_incl_scan(float& Sx, float& Sz,
                                               float& A, float& B, int lane) {
#pragma unroll
    for (int off = 1; off < 64; off <<= 1) {
        float ox = __shfl_up(Sx, off, 64);
        float oz = __shfl_up(Sz, off, 64);
        float oA = __shfl_up(A, off, 64);
        float oB = __shfl_up(B, off, 64);
        if (lane >= off) {
            Sx += ox;
            Sz += oz;
            B = fmaxf(oB + A, B);  // B uses pre-update A
            A = oA + A;
        }
    }
}

// ---------------- main fused kernel -----------------------------------------

__global__ __launch_bounds__(256) void k_main(const float* __restrict__ pose,
                                              const float* __restrict__ bone,
                                              const int* __restrict__ index,
                                              floatx4* __restrict__ outPose4,
                                              float4* __restrict__ vws,
                                              float4* __restrict__ wsAgg) {
    __shared__ float smem[BT * TS_LDS + 12];   // tile + boundary feet slot
    int tid = threadIdx.x, b = blockIdx.x;

    const floatx4* __restrict__ src = (const floatx4*)pose + (size_t)b * F4PB;
    floatx4*       __restrict__ dst = outPose4              + (size_t)b * F4PB;

    // ---- single-pass copy + LDS extract (3456 f4 = 13.5 per thread) -------
    floatx4 r[7];
#pragma unroll
    for (int j = 0; j < 7; ++j) r[j] = src[j * 256 + tid];
#pragma unroll
    for (int j = 0; j < 7; ++j) {
        int idx = j * 256 + tid;
        __builtin_nontemporal_store(r[j], &dst[idx]);
        int tsl = idx / 54;
        int w   = idx - tsl * 54;
        if (w < 21) *(floatx4*)&smem[tsl * TS_LDS + w * 4] = r[j];
    }
#pragma unroll
    for (int j = 0; j < 6; ++j) r[j] = src[(7 + j) * 256 + tid];
#pragma unroll
    for (int j = 0; j < 6; ++j) {
        int idx = (7 + j) * 256 + tid;
        __builtin_nontemporal_store(r[j], &dst[idx]);
        int tsl = idx / 54;
        int w   = idx - tsl * 54;
        if (w < 21) *(floatx4*)&smem[tsl * TS_LDS + w * 4] = r[j];
    }
    if (tid < 128) {
        int idx = 13 * 256 + tid;
        floatx4 q = src[idx];
        __builtin_nontemporal_store(q, &dst[idx]);
        int tsl = idx / 54;
        int w   = idx - tsl * 54;
        if (w < 21) *(floatx4*)&smem[tsl * TS_LDS + w * 4] = q;
    }
    __syncthreads();

    // ---- FK: wave 0 from LDS; tid 64 does boundary timestep from global ---
    float feet[12], fmin;
    if (tid < 64) {
        fk_feet(&smem[tid * TS_LDS], bone, feet, &fmin);
    } else if (tid == 64 && b > 0) {
        float f2[12], m2;
        fk_feet(pose + ((size_t)b * BT - 1) * 216, bone, f2, &m2);
#pragma unroll
        for (int k = 0; k < 12; ++k) smem[BT * TS_LDS + k] = f2[k];
    }
    __syncthreads();

    // ---- velocity + scan operand + unit aggregate (wave 0 only) -----------
    if (tid < 64) {
        int lane = tid;
        int t = b * BT + lane;

        float fp[12];
#pragma unroll
        for (int k = 0; k < 12; ++k) fp[k] = __shfl_up(feet[k], 1, 64);
        if (lane == 0 && b > 0) {
#pragma unroll
            for (int k = 0; k < 12; ++k) fp[k] = smem[BT * TS_LDS + k];
        }

        float vx, vy, vz;
        if (t == 0) {
            vx = 0.f; vy = GRAV_Y; vz = 0.f;
        } else {
            int idx = index[t];
            vx = sel_foot(fp, idx, 0) - sel_foot(feet, idx, 0);
            vy = GRAV_Y + sel_foot(fp, idx, 1) - sel_foot(feet, idx, 1);
            vz = sel_foot(fp, idx, 2) - sel_foot(feet, idx, 2);
        }
        float A = vy;
        float B = FLOOR_YC - fmin;
        vws[t] = make_float4(vx, vz, A, B);

        float Sx = vx, Sz = vz;
        wave_incl_scan(Sx, Sz, A, B, lane);
        if (lane == 63) wsAgg[b] = make_float4(Sx, Sz, A, B);
    }
}

// Scan of 2048 unit aggregates -> per-unit entering state (x, z, root_y).
__global__ __launch_bounds__(1024) void k_phase2(const float4* __restrict__ wsAgg,
                                                 float4* __restrict__ wsIn) {
    __shared__ float sx[1024], sz[1024], sa[1024], sb[1024];
    int tid = threadIdx.x;

    float4 a0 = wsAgg[2 * tid];
    float4 a1 = wsAgg[2 * tid + 1];
    float cx = a0.x + a1.x;
    float cz = a0.y + a1.y;
    float cb = fmaxf(a0.w + a1.z, a1.w);
    float ca = a0.z + a1.z;
    sx[tid] = cx; sz[tid] = cz; sa[tid] = ca; sb[tid] = cb;
    __syncthreads();

    for (int off = 1; off < 1024; off <<= 1) {
        float px = 0.f, pz = 0.f, pa = 0.f, pb = NEG_INF;
        bool h = (tid >= off);
        if (h) { px = sx[tid - off]; pz = sz[tid - off]; pa = sa[tid - off]; pb = sb[tid - off]; }
        __syncthreads();
        if (h) {
            float qa = sa[tid], qb = sb[tid];
            sx[tid] = px + sx[tid];
            sz[tid] = pz + sz[tid];
            sb[tid] = fmaxf(pb + qa, qb);
            sa[tid] = pa + qa;
        }
        __syncthreads();
    }

    float ex = 0.f, ez = 0.f, ea = 0.f, eb = NEG_INF;
    if (tid > 0) { ex = sx[tid - 1]; ez = sz[tid - 1]; ea = sa[tid - 1]; eb = sb[tid - 1]; }

    wsIn[2 * tid] = make_float4(ex, ez, fmaxf(ea, eb), 0.f);

    float fx = ex + a0.x;
    float fz = ez + a0.y;
    float fb = fmaxf(eb + a0.z, a0.w);
    float fa = ea + a0.z;
    wsIn[2 * tid + 1] = make_float4(fx, fz, fmaxf(fa, fb), 0.f);
}

// Final: each wave handles one 64-step unit; no cross-wave composition needed.
__global__ __launch_bounds__(256) void k_phase3(const float4* __restrict__ vws,
                                                const float4* __restrict__ wsIn,
                                                float* __restrict__ trans) {
    int tid = threadIdx.x, bk = blockIdx.x;
    int lane = tid & 63, wv = tid >> 6;
    int u = bk * 4 + wv;
    int t = u * 64 + lane;

    float4 v = vws[t];
    float ix = v.x, iz = v.y, iA = v.z, iB = v.w;
    wave_incl_scan(ix, iz, iA, iB, lane);

    float4 bin = wsIn[u];
    trans[(size_t)t * 3 + 0] = bin.x + ix;
    trans[(size_t)t * 3 + 1] = fmaxf(bin.z + iA, iB);
    trans[(size_t)t * 3 + 2] = bin.y + iz;
}

// ---------------- launch -----------------------------------------------------

extern "C" void kernel_launch(void* const* d_in, const int* in_sizes, int n_in,
                              void* d_out, int out_size, void* d_ws, size_t ws_size,
                              hipStream_t stream) {
    const float* pose  = (const float*)d_in[0];
    const float* bone  = (const float*)d_in[1];
    const int*   index = (const int*)d_in[2];
    float* out   = (float*)d_out;
    float* trans = out + POSE_FLTS;

    float4* vws   = (float4*)d_ws;         // T entries (2 MB)
    float4* wsAgg = vws + T_TOTAL;         // NB entries
    float4* wsIn  = wsAgg + NB;            // NB entries

    k_main  <<<NB, 256, 0, stream>>>(pose, bone, index, (floatx4*)out, vws, wsAgg);
    k_phase2<<<1, 1024, 0, stream>>>(wsAgg, wsIn);
    k_phase3<<<T_TOTAL / 256, 256, 0, stream>>>(vws, wsIn, trans);
}